// Round 1
// 460.038 us; speedup vs baseline: 1.0254x; 1.0254x over previous
//
#include <hip/hip_runtime.h>

// ---------------------------------------------------------------------------
// StackedLSTMCell: L=2, B=16384, S=512.
//   per layer: z = x@W + h_tm1@U + b ; (i,f,g,o) = split(z)
//              c = sig(f)*c_tm1 + sig(i)*tanh(g) ; h = sig(o)*tanh(c)
//   h_tm1 = prev_c[l], c_tm1 = prev_h[l] (NNI naming swap). x_{l+1} = c_l.
// GEMM: 256x256 tile, BK=64, 8 waves (2M x 4N), 8-phase-per-2-K-tiles schedule
//   (T3+T4 counted vmcnt, T2 LDS XOR-swizzle, T5 setprio, T1 XCD-affine grid).
//   Gate-interleaved N permutation (repack_w) keeps the LSTM epilogue
//   lane-local: wave's 64 N-cols = gates 0..3 of the same 16 hidden units.
// ---------------------------------------------------------------------------

#define B_DIM   16384
#define S_DIM   512
#define K_DIM   1024          // concat K = S (input) + S (recurrent)
#define N_DIM   2048          // 4 gates * S
#define BS      (B_DIM * S_DIM)
#define NT      16            // K tiles of 64

typedef __bf16 bf16x8 __attribute__((ext_vector_type(8)));
typedef float  f32x4  __attribute__((ext_vector_type(4)));

__device__ __forceinline__ void async16(const void* g, void* l) {
    __builtin_amdgcn_global_load_lds(
        (const __attribute__((address_space(1))) void*)g,
        (__attribute__((address_space(3))) void*)l,
        16, 0, 0);
}

__device__ __forceinline__ float sigm(float x) { return 1.f / (1.f + __expf(-x)); }
__device__ __forceinline__ float tanh_f(float x) { return 1.f - 2.f / (__expf(2.f * x) + 1.f); }

// ---------------------------------------------------------------------------
// Repack weights: Wcat[l][new_n][k] (bf16), k<512 from kernels, k>=512 from
// rec_kernels. new_n = (s/16)*64 + gate*16 + (s%16), orig col = gate*512 + s.
// LDS tile transpose for coalescing. Grid: 1024 blocks x 256. (unchanged)
// ---------------------------------------------------------------------------
__global__ __launch_bounds__(256) void repack_w(const float* __restrict__ kern,
                                                const float* __restrict__ rker,
                                                __bf16* __restrict__ Wcat) {
    int bid   = blockIdx.x;
    int ntile = bid & 31;        // 32 tiles of 64 orig cols
    int kt    = (bid >> 5) & 7;  // 8 tiles of 64 k
    int srcm  = (bid >> 8) & 1;  // 0 = kern, 1 = rec
    int l     = bid >> 9;

    __shared__ float tile[64][65];
    const float* src = (srcm ? rker : kern) + l * (S_DIM * N_DIM);
    int k0 = kt * 64, n0 = ntile * 64;
    int t = threadIdx.x;

    for (int i = 0; i < 4; ++i) {
        int lin4 = i * 256 + t;          // 1024 float4 slots
        int row  = lin4 >> 4;
        int c4   = (lin4 & 15) << 2;
        float4 v = *(const float4*)(src + (k0 + row) * N_DIM + n0 + c4);
        tile[row][c4]     = v.x;
        tile[row][c4 + 1] = v.y;
        tile[row][c4 + 2] = v.z;
        tile[row][c4 + 3] = v.w;
    }
    __syncthreads();

    int gate = n0 >> 9;                  // whole tile one gate (64 | 512)
    for (int it = 0; it < 2; ++it) {
        int slot = it * 256 + t;         // 512 slots: 64 cols x 8 k-segs
        int c    = slot >> 3;
        int seg  = slot & 7;
        int n    = n0 + c;
        int s    = n & 511;
        int new_n = ((s >> 4) << 6) + (gate << 4) + (s & 15);
        int kc = srcm * 512 + k0 + seg * 8;
        bf16x8 o;
        #pragma unroll
        for (int j = 0; j < 8; ++j) o[j] = (__bf16)tile[seg * 8 + j][c];
        *(bf16x8*)(Wcat + (size_t)(l * N_DIM + new_n) * K_DIM + kc) = o;
    }
}

// ---------------------------------------------------------------------------
// Convert activations to bf16 concat layout. (unchanged)
//   sec0: x -> A0[:,0:512]; sec1: prev_c[0] -> A0[:,512:]; sec2: prev_c[1] -> A1[:,512:]
// ---------------------------------------------------------------------------
__global__ __launch_bounds__(256) void convert_A(const float* __restrict__ x,
                                                 const float* __restrict__ prev_c,
                                                 __bf16* __restrict__ A0,
                                                 __bf16* __restrict__ A1) {
    int id  = blockIdx.x * 256 + threadIdx.x;
    int sec = id >> 20;
    int e   = id & ((1 << 20) - 1);
    int r   = e >> 6;
    int c   = (e & 63) << 3;
    const float* src;
    __bf16* dst;
    if (sec == 0)      { src = x + (size_t)r * S_DIM + c;            dst = A0 + (size_t)r * K_DIM + c; }
    else if (sec == 1) { src = prev_c + (size_t)r * S_DIM + c;       dst = A0 + (size_t)r * K_DIM + 512 + c; }
    else               { src = prev_c + (size_t)BS + (size_t)r * S_DIM + c; dst = A1 + (size_t)r * K_DIM + 512 + c; }
    float4 v0 = *(const float4*)(src);
    float4 v1 = *(const float4*)(src + 4);
    bf16x8 o;
    o[0] = (__bf16)v0.x; o[1] = (__bf16)v0.y; o[2] = (__bf16)v0.z; o[3] = (__bf16)v0.w;
    o[4] = (__bf16)v1.x; o[5] = (__bf16)v1.y; o[6] = (__bf16)v1.z; o[7] = (__bf16)v1.w;
    *(bf16x8*)dst = o;
}

// ---------------------------------------------------------------------------
// Fused GEMM + LSTM cell, 256x256 tile / BK=64 / 8 waves / 8-phase schedule.
//
// LDS (128 KiB): buf b (64 KiB each): A-half h at b*64K + h*16K (128 rows x
// 128 B), B-half h at b*64K + 32K + h*16K. T2 swizzle: element (row r, byte c)
// stored at byte (r*128 + (c ^ ((r&7)<<4))); global_load_lds writes linearly,
// so the SOURCE address is inverse-swizzled (same involution) per rule #21.
//
// Phase schedule per K-tile t (buf cur = t&1), quadrants (mh,nh):
//   P0 (0,0): ds: a<-mh0 (8), b0<-nh0 (4); stage B-h0(t+1)->nxt; BAR; MFMA; BAR
//   P1 (0,1): ds: b1<-nh1 (4);             stage B-h1(t+1)->nxt; BAR; MFMA; BAR
//   P2 (1,1): ds: a<-mh1 (8);                                    BAR; MFMA; BAR
//   P3 (1,0): ds: b0<-nh0 reload (4);      stage A-h0/h1(t+2)->cur;
//             BAR; MFMA; vmcnt(4); BAR
// Region deaths: A(t) dead after P2's post-MFMA barrier (reads at P0,P2) ->
// A(t+2) stage at P3 legal. B(t) dead after P3 (reads P0,P1,P3) -> B(t+2)
// staged at (t+1).P0/P1 legal. vmcnt(4) leaves A(t+2)'s 4 loads in flight
// across every tile boundary (never drains to 0 except t==NT-2).
// ---------------------------------------------------------------------------
__global__ __launch_bounds__(512, 2) void lstm_gemm(const __bf16* __restrict__ A,
                                                    const __bf16* __restrict__ W,
                                                    const float* __restrict__ c_tm1p,
                                                    const float* __restrict__ bias,
                                                    float* __restrict__ outh,
                                                    float* __restrict__ outc,
                                                    __bf16* __restrict__ A_next) {
    __shared__ __align__(16) char smem[131072];

    int tid  = threadIdx.x;
    int w    = tid >> 6, lane = tid & 63;
    int wm   = w >> 2, wn = w & 3;          // 2 x 4 waves
    int l15  = lane & 15, quad = lane >> 4;
    int wh   = wn >> 1, wn1 = wn & 1;

    int bid   = blockIdx.x;
    int rowB0 = (bid & 7) << 8;             // XCD-affine: bid%8 -> n-panel (T1)
    int rowA0 = (bid >> 3) << 8;

    // ---- staging geometry (per-thread constants) ----
    // half-tile = 128 rows x 128 B = 16 KB = 2 chunks x (512 thr x 16 B).
    // chunk c: lds flat = c*8192 + tid*16 -> row = c*64 + tid/8, byte = (tid&7)*16.
    int r0   = tid >> 3;                    // 0..63
    int bo   = (tid & 7) << 4;              // 0..112
    int bsrc = bo ^ ((r0 & 7) << 4);        // inverse-swizzled source byte
    const __bf16* aSrc = A + (size_t)(rowA0 + r0) * K_DIM + (bsrc >> 1);
    const __bf16* bSrc = W + (size_t)(rowB0 + r0) * K_DIM + (bsrc >> 1);
    char* smb = smem;
    int dA0 = tid * 16;

    // ---- fragment-read constants ----
    int arow = l15 * 128;
    int axor = (l15 & 7) << 4;              // T2 swizzle (row&7 == l15&7 here)
    int kq0 = (quad * 16) ^ axor;           // ks=0
    int kq1 = (64 + quad * 16) ^ axor;      // ks=1

#define STAGE_A(BUF, H, KO) do { \
    async16(aSrc + (size_t)((H) * 128) * K_DIM + (KO),      smb + (BUF) * 65536 + (H) * 16384 + dA0); \
    async16(aSrc + (size_t)((H) * 128 + 64) * K_DIM + (KO), smb + (BUF) * 65536 + (H) * 16384 + 8192 + dA0); \
} while (0)
#define STAGE_B(BUF, H, KO) do { \
    async16(bSrc + (size_t)((H) * 128) * K_DIM + (KO),      smb + (BUF) * 65536 + 32768 + (H) * 16384 + dA0); \
    async16(bSrc + (size_t)((H) * 128 + 64) * K_DIM + (KO), smb + (BUF) * 65536 + 32768 + (H) * 16384 + 8192 + dA0); \
} while (0)
#define LOAD_A(MH) do { \
    _Pragma("unroll") \
    for (int mt = 0; mt < 4; ++mt) { \
        const char* p_ = Abase + ((MH) * 64 + mt * 16) * 128 + arow; \
        a[mt][0] = *(const bf16x8*)(p_ + kq0); \
        a[mt][1] = *(const bf16x8*)(p_ + kq1); \
    } } while (0)
#define LOAD_B(DST, NH) do { \
    _Pragma("unroll") \
    for (int nt = 0; nt < 2; ++nt) { \
        const char* p_ = Bbase + (wn1 * 64 + (NH) * 32 + nt * 16) * 128 + arow; \
        DST[nt][0] = *(const bf16x8*)(p_ + kq0); \
        DST[nt][1] = *(const bf16x8*)(p_ + kq1); \
    } } while (0)
#define MFMA_Q(MH, NH, BB) do { \
    _Pragma("unroll") \
    for (int mt = 0; mt < 4; ++mt) \
    _Pragma("unroll") \
    for (int nt = 0; nt < 2; ++nt) { \
        acc[MH][NH][mt][nt] = __builtin_amdgcn_mfma_f32_16x16x32_bf16(a[mt][0], BB[nt][0], acc[MH][NH][mt][nt], 0, 0, 0); \
        acc[MH][NH][mt][nt] = __builtin_amdgcn_mfma_f32_16x16x32_bf16(a[mt][1], BB[nt][1], acc[MH][NH][mt][nt], 0, 0, 0); \
    } } while (0)
#define BAR   __builtin_amdgcn_s_barrier()
#define PRIO1 __builtin_amdgcn_s_setprio(1)
#define PRIO0 __builtin_amdgcn_s_setprio(0)
#define VMCNT(N) do { asm volatile("s_waitcnt vmcnt(" #N ")" ::: "memory"); \
                      __builtin_amdgcn_sched_barrier(0); } while (0)

    f32x4 acc[2][2][4][2];                  // [mh][nh][mt][nt]
    #pragma unroll
    for (int i = 0; i < 2; ++i)
        #pragma unroll
        for (int j = 0; j < 2; ++j)
            #pragma unroll
            for (int mt = 0; mt < 4; ++mt)
                #pragma unroll
                for (int nt = 0; nt < 2; ++nt)
                    acc[i][j][mt][nt] = (f32x4){0.f, 0.f, 0.f, 0.f};

    bf16x8 a[4][2], b0[2][2], b1[2][2];
    const char *Abase, *Bbase;

    // ---- prologue: tile 0 (8 loads) + tile 1's A pair ("t-1.P3" slot) ----
    STAGE_A(0, 0, 0); STAGE_A(0, 1, 0);
    STAGE_B(0, 0, 0); STAGE_B(0, 1, 0);
    STAGE_A(1, 0, 64); STAGE_A(1, 1, 64);
    VMCNT(4);                               // tile 0 resident; A(1) in flight
    BAR;

    for (int t = 0; t < NT; ++t) {
        int cur = t & 1, nxt = cur ^ 1;
        Abase = smb + cur * 65536 + wm * 16384;
        Bbase = smb + cur * 65536 + 32768 + wh * 16384;
        int ka = (t + 1) * 64, kb = (t + 2) * 64;

        // P0: quadrant (0,0)
        LOAD_A(0); LOAD_B(b0, 0);
        if (t < NT - 1) STAGE_B(nxt, 0, ka);
        BAR; PRIO1; MFMA_Q(0, 0, b0); PRIO0; BAR;

        // P1: quadrant (0,1)
        LOAD_B(b1, 1);
        if (t < NT - 1) STAGE_B(nxt, 1, ka);
        BAR; PRIO1; MFMA_Q(0, 1, b1); PRIO0; BAR;

        // P2: quadrant (1,1)
        LOAD_A(1);
        BAR; PRIO1; MFMA_Q(1, 1, b1); PRIO0; BAR;

        // P3: quadrant (1,0)
        LOAD_B(b0, 0);                      // reload (same data, region unmodified)
        if (t < NT - 2) { STAGE_A(cur, 0, kb); STAGE_A(cur, 1, kb); }
        BAR; PRIO1; MFMA_Q(1, 0, b0); PRIO0;
        if (t < NT - 2)       VMCNT(4);     // tile t+1 resident; A(t+2) in flight
        else if (t == NT - 2) VMCNT(0);     // last prefetch: drain
        BAR;
    }

    // ---- epilogue: lane-local LSTM cell ----
    // col u: wave's 64 N-cols = gates 0..3 (g = nh*2+nt) of 16 hidden units.
    int u = (((bid & 7) * 4 + wn) << 4) + l15;
    float bg0 = bias[0 * S_DIM + u];
    float bg1 = bias[1 * S_DIM + u];
    float bg2 = bias[2 * S_DIM + u];
    float bg3 = bias[3 * S_DIM + u];

    #pragma unroll
    for (int mh = 0; mh < 2; ++mh)
        #pragma unroll
        for (int mt = 0; mt < 4; ++mt) {
            int Rb = rowA0 + wm * 128 + mh * 64 + mt * 16 + quad * 4;
            #pragma unroll
            for (int reg = 0; reg < 4; ++reg) {
                int R = Rb + reg;
                float zi = acc[mh][0][mt][0][reg] + bg0;
                float zf = acc[mh][0][mt][1][reg] + bg1;
                float zg = acc[mh][1][mt][0][reg] + bg2;
                float zo = acc[mh][1][mt][1][reg] + bg3;
                float ct = c_tm1p[(size_t)R * S_DIM + u];
                float cv = sigm(zf) * ct + sigm(zi) * tanh_f(zg);
                float hv = sigm(zo) * tanh_f(cv);
                outh[(size_t)R * S_DIM + u] = hv;
                outc[(size_t)R * S_DIM + u] = cv;
                if (A_next) A_next[(size_t)R * K_DIM + u] = (__bf16)cv;
            }
        }

#undef STAGE_A
#undef STAGE_B
#undef LOAD_A
#undef LOAD_B
#undef MFMA_Q
#undef BAR
#undef PRIO1
#undef PRIO0
#undef VMCNT
}

// ---------------------------------------------------------------------------
extern "C" void kernel_launch(void* const* d_in, const int* in_sizes, int n_in,
                              void* d_out, int out_size, void* d_ws, size_t ws_size,
                              hipStream_t stream) {
    const float* x      = (const float*)d_in[0];
    const float* prev_c = (const float*)d_in[1];
    const float* prev_h = (const float*)d_in[2];
    const float* kern   = (const float*)d_in[3];
    const float* rker   = (const float*)d_in[4];
    const float* bias   = (const float*)d_in[5];
    float* out = (float*)d_out;

    char* ws = (char*)d_ws;
    __bf16* Wcat = (__bf16*)ws;                              // 2*2048*1024 bf16 = 8 MB
    __bf16* A0   = (__bf16*)(ws + (size_t)8  * 1024 * 1024); // 16384*1024 bf16 = 32 MB
    __bf16* A1   = (__bf16*)(ws + (size_t)40 * 1024 * 1024); // 32 MB

    convert_A<<<12288, 256, 0, stream>>>(x, prev_c, A0, A1);
    repack_w<<<1024, 256, 0, stream>>>(kern, rker, Wcat);

    // grid: 512 blocks; bid%8 = n-panel (XCD-affine), bid/8 = m-panel
    // layer 0: h_tm1 = prev_c[0] (already in A0), c_tm1 = prev_h[0]
    lstm_gemm<<<512, 512, 0, stream>>>(A0, Wcat,
                                       prev_h,              bias,
                                       out,                 out + (size_t)BS,
                                       A1);
    // layer 1: x = c0 (A1 low half, written by layer-0 epilogue)
    lstm_gemm<<<512, 512, 0, stream>>>(A1, Wcat + (size_t)N_DIM * K_DIM,
                                       prev_h + (size_t)BS, bias + N_DIM,
                                       out + (size_t)2 * BS, out + (size_t)3 * BS,
                                       nullptr);
}

// Round 2
// 402.674 us; speedup vs baseline: 1.1715x; 1.1425x over previous
//
#include <hip/hip_runtime.h>

// ---------------------------------------------------------------------------
// StackedLSTMCell: L=2, B=16384, S=512.
//   per layer: z = x@W + h_tm1@U + b ; (i,f,g,o) = split(z)
//              c = sig(f)*c_tm1 + sig(i)*tanh(g) ; h = sig(o)*tanh(c)
//   h_tm1 = prev_c[l], c_tm1 = prev_h[l] (NNI naming swap). x_{l+1} = c_l.
// GEMM: 256x256 tile, BK=64, 8 waves (2M x 4N), 4-phase-per-K-tile schedule
//   (T3+T4 counted vmcnt, T2 LDS XOR-swizzle, T5 setprio).
//   Grid: M-major within n-panel (all XCDs cooperate on one B-panel; A
//   streamed once collectively -> min HBM fetch; the R1 XCD-affine map made
//   each XCD re-stream all of A: FETCH 84->152MB. Reverted).
//   c_tm1 tile prefetched into the dead LDS buffer during the last K-tile.
// ---------------------------------------------------------------------------

#define B_DIM   16384
#define S_DIM   512
#define K_DIM   1024          // concat K = S (input) + S (recurrent)
#define N_DIM   2048          // 4 gates * S
#define BS      (B_DIM * S_DIM)
#define NT      16            // K tiles of 64

typedef __bf16 bf16x8 __attribute__((ext_vector_type(8)));
typedef float  f32x4  __attribute__((ext_vector_type(4)));

__device__ __forceinline__ void async16(const void* g, void* l) {
    __builtin_amdgcn_global_load_lds(
        (const __attribute__((address_space(1))) void*)g,
        (__attribute__((address_space(3))) void*)l,
        16, 0, 0);
}

__device__ __forceinline__ float sigm(float x) { return 1.f / (1.f + __expf(-x)); }
__device__ __forceinline__ float tanh_f(float x) { return 1.f - 2.f / (__expf(2.f * x) + 1.f); }

// ---------------------------------------------------------------------------
// Repack weights: Wcat[l][new_n][k] (bf16), k<512 from kernels, k>=512 from
// rec_kernels. new_n = (s/16)*64 + gate*16 + (s%16), orig col = gate*512 + s.
// ---------------------------------------------------------------------------
__global__ __launch_bounds__(256) void repack_w(const float* __restrict__ kern,
                                                const float* __restrict__ rker,
                                                __bf16* __restrict__ Wcat) {
    int bid   = blockIdx.x;
    int ntile = bid & 31;
    int kt    = (bid >> 5) & 7;
    int srcm  = (bid >> 8) & 1;
    int l     = bid >> 9;

    __shared__ float tile[64][65];
    const float* src = (srcm ? rker : kern) + l * (S_DIM * N_DIM);
    int k0 = kt * 64, n0 = ntile * 64;
    int t = threadIdx.x;

    for (int i = 0; i < 4; ++i) {
        int lin4 = i * 256 + t;
        int row  = lin4 >> 4;
        int c4   = (lin4 & 15) << 2;
        float4 v = *(const float4*)(src + (k0 + row) * N_DIM + n0 + c4);
        tile[row][c4]     = v.x;
        tile[row][c4 + 1] = v.y;
        tile[row][c4 + 2] = v.z;
        tile[row][c4 + 3] = v.w;
    }
    __syncthreads();

    int gate = n0 >> 9;
    for (int it = 0; it < 2; ++it) {
        int slot = it * 256 + t;
        int c    = slot >> 3;
        int seg  = slot & 7;
        int n    = n0 + c;
        int s    = n & 511;
        int new_n = ((s >> 4) << 6) + (gate << 4) + (s & 15);
        int kc = srcm * 512 + k0 + seg * 8;
        bf16x8 o;
        #pragma unroll
        for (int j = 0; j < 8; ++j) o[j] = (__bf16)tile[seg * 8 + j][c];
        *(bf16x8*)(Wcat + (size_t)(l * N_DIM + new_n) * K_DIM + kc) = o;
    }
}

// ---------------------------------------------------------------------------
// Convert activations to bf16 concat layout. (unchanged)
// ---------------------------------------------------------------------------
__global__ __launch_bounds__(256) void convert_A(const float* __restrict__ x,
                                                 const float* __restrict__ prev_c,
                                                 __bf16* __restrict__ A0,
                                                 __bf16* __restrict__ A1) {
    int id  = blockIdx.x * 256 + threadIdx.x;
    int sec = id >> 20;
    int e   = id & ((1 << 20) - 1);
    int r   = e >> 6;
    int c   = (e & 63) << 3;
    const float* src;
    __bf16* dst;
    if (sec == 0)      { src = x + (size_t)r * S_DIM + c;            dst = A0 + (size_t)r * K_DIM + c; }
    else if (sec == 1) { src = prev_c + (size_t)r * S_DIM + c;       dst = A0 + (size_t)r * K_DIM + 512 + c; }
    else               { src = prev_c + (size_t)BS + (size_t)r * S_DIM + c; dst = A1 + (size_t)r * K_DIM + 512 + c; }
    float4 v0 = *(const float4*)(src);
    float4 v1 = *(const float4*)(src + 4);
    bf16x8 o;
    o[0] = (__bf16)v0.x; o[1] = (__bf16)v0.y; o[2] = (__bf16)v0.z; o[3] = (__bf16)v0.w;
    o[4] = (__bf16)v1.x; o[5] = (__bf16)v1.y; o[6] = (__bf16)v1.z; o[7] = (__bf16)v1.w;
    *(bf16x8*)dst = o;
}

// ---------------------------------------------------------------------------
// Fused GEMM + LSTM cell, 256x256 tile / BK=64 / 8 waves / 4 phases per K-tile.
//
// LDS (128 KiB): buf b (64 KiB): A-half h at b*64K + h*16K (128 rows x 128 B),
// B-half h at b*64K + 32K + h*16K. T2 swizzle: (row r, byte c) stored at
// r*128 + (c ^ ((r&7)<<4)); global_load_lds writes linearly, so SOURCE is
// inverse-swizzled (rule #21).
//
// Phases for K-tile t (cur = t&1), quadrants (mh,nh):
//   P0 (0,0): ds: a<-mh0 (8), b0<-nh0 (4); t<NT-1: stage B-h0(t+1)->nxt,
//             t==NT-1: stage c_tm1 tile (64KB fp32) -> nxt buf (dead).
//   P1 (0,1): ds: b1<-nh1 (4);             stage B-h1(t+1)->nxt
//   P2 (1,1): ds: a<-mh1 (8)
//   P3 (1,0): no ds (b0 still live);       stage A-h0/h1(t+2)->cur;
//             VMCNT(4) after MFMA (tile t+1 resident, A(t+2) in flight).
// Each phase: [ds + stage] BAR [setprio(1) 16xMFMA setprio(0)] BAR.
// ---------------------------------------------------------------------------
__global__ __launch_bounds__(512, 2) void lstm_gemm(const __bf16* __restrict__ A,
                                                    const __bf16* __restrict__ W,
                                                    const float* __restrict__ c_tm1p,
                                                    const float* __restrict__ bias,
                                                    float* __restrict__ outh,
                                                    float* __restrict__ outc,
                                                    __bf16* __restrict__ A_next) {
    __shared__ __align__(16) char smem[131072];

    int tid  = threadIdx.x;
    int w    = tid >> 6, lane = tid & 63;
    int wm   = w >> 2, wn = w & 3;          // 2 x 4 waves
    int l15  = lane & 15, quad = lane >> 4;
    int wh   = wn >> 1, wn1 = wn & 1;

    int bid   = blockIdx.x;
    int rowA0 = (bid & 63) << 8;            // M-major: A streamed once globally
    int rowB0 = (bid >> 6) << 8;            // n-panel changes every 64 blocks

    // ---- staging geometry ----
    int r0   = tid >> 3;                    // 0..63
    int bo   = (tid & 7) << 4;              // 0..112
    int bsrc = bo ^ ((r0 & 7) << 4);        // inverse-swizzled source byte
    const __bf16* aSrc = A + (size_t)(rowA0 + r0) * K_DIM + (bsrc >> 1);
    const __bf16* bSrc = W + (size_t)(rowB0 + r0) * K_DIM + (bsrc >> 1);
    const float*  cSrc = c_tm1p + (size_t)rowA0 * S_DIM + (rowB0 >> 2); // u0 = rowB0/4
    char* smb = smem;
    int dA0 = tid * 16;

    // ---- fragment-read constants ----
    int arow = l15 * 128;
    int axor = (l15 & 7) << 4;
    int kq0 = (quad * 16) ^ axor;
    int kq1 = (64 + quad * 16) ^ axor;

#define STAGE_A(BUF, H, KO) do { \
    async16(aSrc + (size_t)((H) * 128) * K_DIM + (KO),      smb + (BUF) * 65536 + (H) * 16384 + dA0); \
    async16(aSrc + (size_t)((H) * 128 + 64) * K_DIM + (KO), smb + (BUF) * 65536 + (H) * 16384 + 8192 + dA0); \
} while (0)
#define STAGE_B(BUF, H, KO) do { \
    async16(bSrc + (size_t)((H) * 128) * K_DIM + (KO),      smb + (BUF) * 65536 + 32768 + (H) * 16384 + dA0); \
    async16(bSrc + (size_t)((H) * 128 + 64) * K_DIM + (KO), smb + (BUF) * 65536 + 32768 + (H) * 16384 + 8192 + dA0); \
} while (0)
// c_tm1 tile: 256 rows x 64 fp32 = 64KB -> buf BUF (linear). slot=ci*512+tid:
// row = slot>>4, seg = slot&15 -> src row*512 + seg*4 floats; dst linear.
#define STAGE_C(BUF) do { \
    _Pragma("unroll") \
    for (int ci = 0; ci < 8; ++ci) { \
        int slot_ = ci * 512 + tid; \
        int row_ = slot_ >> 4, seg_ = slot_ & 15; \
        async16(cSrc + (size_t)row_ * S_DIM + seg_ * 4, smb + (BUF) * 65536 + ci * 8192 + dA0); \
    } } while (0)
#define LOAD_A(MH) do { \
    _Pragma("unroll") \
    for (int mt = 0; mt < 4; ++mt) { \
        const char* p_ = Abase + ((MH) * 64 + mt * 16) * 128 + arow; \
        a[mt][0] = *(const bf16x8*)(p_ + kq0); \
        a[mt][1] = *(const bf16x8*)(p_ + kq1); \
    } } while (0)
#define LOAD_B(DST, NH) do { \
    _Pragma("unroll") \
    for (int nt = 0; nt < 2; ++nt) { \
        const char* p_ = Bbase + (wn1 * 64 + (NH) * 32 + nt * 16) * 128 + arow; \
        DST[nt][0] = *(const bf16x8*)(p_ + kq0); \
        DST[nt][1] = *(const bf16x8*)(p_ + kq1); \
    } } while (0)
#define MFMA_Q(MH, NH, BB) do { \
    _Pragma("unroll") \
    for (int mt = 0; mt < 4; ++mt) \
    _Pragma("unroll") \
    for (int nt = 0; nt < 2; ++nt) { \
        acc[MH][NH][mt][nt] = __builtin_amdgcn_mfma_f32_16x16x32_bf16(a[mt][0], BB[nt][0], acc[MH][NH][mt][nt], 0, 0, 0); \
        acc[MH][NH][mt][nt] = __builtin_amdgcn_mfma_f32_16x16x32_bf16(a[mt][1], BB[nt][1], acc[MH][NH][mt][nt], 0, 0, 0); \
    } } while (0)
#define BAR   __builtin_amdgcn_s_barrier()
#define PRIO1 __builtin_amdgcn_s_setprio(1)
#define PRIO0 __builtin_amdgcn_s_setprio(0)
#define VMCNT(N) do { asm volatile("s_waitcnt vmcnt(" #N ")" ::: "memory"); \
                      __builtin_amdgcn_sched_barrier(0); } while (0)

    f32x4 acc[2][2][4][2];                  // [mh][nh][mt][nt]
    #pragma unroll
    for (int i = 0; i < 2; ++i)
        #pragma unroll
        for (int j = 0; j < 2; ++j)
            #pragma unroll
            for (int mt = 0; mt < 4; ++mt)
                #pragma unroll
                for (int nt = 0; nt < 2; ++nt)
                    acc[i][j][mt][nt] = (f32x4){0.f, 0.f, 0.f, 0.f};

    bf16x8 a[4][2], b0[2][2], b1[2][2];
    const char *Abase, *Bbase;

    // ---- prologue: tile 0 (8 loads) + tile 1's A pair ----
    STAGE_A(0, 0, 0); STAGE_A(0, 1, 0);
    STAGE_B(0, 0, 0); STAGE_B(0, 1, 0);
    STAGE_A(1, 0, 64); STAGE_A(1, 1, 64);
    VMCNT(4);                               // tile 0 resident; A(1) in flight
    BAR;

    for (int t = 0; t < NT; ++t) {
        int cur = t & 1, nxt = cur ^ 1;
        Abase = smb + cur * 65536 + wm * 16384;
        Bbase = smb + cur * 65536 + 32768 + wh * 16384;
        int ka = (t + 1) * 64, kb = (t + 2) * 64;

        // P0: quadrant (0,0)
        LOAD_A(0); LOAD_B(b0, 0);
        if (t < NT - 1) STAGE_B(nxt, 0, ka);
        else            STAGE_C(nxt);       // c_tm1 tile into dead buffer
        BAR; PRIO1; MFMA_Q(0, 0, b0); PRIO0; BAR;

        // P1: quadrant (0,1)
        LOAD_B(b1, 1);
        if (t < NT - 1) STAGE_B(nxt, 1, ka);
        BAR; PRIO1; MFMA_Q(0, 1, b1); PRIO0; BAR;

        // P2: quadrant (1,1)
        LOAD_A(1);
        BAR; PRIO1; MFMA_Q(1, 1, b1); PRIO0; BAR;

        // P3: quadrant (1,0) — b0 still live, no ds reads
        if (t < NT - 2) { STAGE_A(cur, 0, kb); STAGE_A(cur, 1, kb); }
        BAR; PRIO1; MFMA_Q(1, 0, b0); PRIO0;
        if (t < NT - 2)       VMCNT(4);     // tile t+1 resident; A(t+2) in flight
        else if (t == NT - 2) VMCNT(0);     // last weight/act prefetch: drain
        BAR;
    }

    VMCNT(0);                               // c_tm1 DMA complete
    BAR;

    // ---- epilogue: lane-local LSTM cell; c_tm1 from LDS ----
    // wave's 64 N-cols = gates 0..3 (g = nh*2+nt) of 16 hidden units.
    const float* cLds = (const float*)smb;  // nxt buf at t=NT-1 is buf 0
    int u    = (((rowB0 >> 6) + wn) << 4) + l15;
    int ccol = wn * 16 + l15;
    float bg0 = bias[0 * S_DIM + u];
    float bg1 = bias[1 * S_DIM + u];
    float bg2 = bias[2 * S_DIM + u];
    float bg3 = bias[3 * S_DIM + u];

    #pragma unroll
    for (int mh = 0; mh < 2; ++mh)
        #pragma unroll
        for (int mt = 0; mt < 4; ++mt) {
            int rloc = wm * 128 + mh * 64 + mt * 16 + quad * 4;
            int Rb   = rowA0 + rloc;
            #pragma unroll
            for (int reg = 0; reg < 4; ++reg) {
                int R = Rb + reg;
                float zi = acc[mh][0][mt][0][reg] + bg0;
                float zf = acc[mh][0][mt][1][reg] + bg1;
                float zg = acc[mh][1][mt][0][reg] + bg2;
                float zo = acc[mh][1][mt][1][reg] + bg3;
                float ct = cLds[(rloc + reg) * 64 + ccol];
                float cv = sigm(zf) * ct + sigm(zi) * tanh_f(zg);
                float hv = sigm(zo) * tanh_f(cv);
                outh[(size_t)R * S_DIM + u] = hv;
                outc[(size_t)R * S_DIM + u] = cv;
                if (A_next) A_next[(size_t)R * K_DIM + u] = (__bf16)cv;
            }
        }

#undef STAGE_A
#undef STAGE_B
#undef STAGE_C
#undef LOAD_A
#undef LOAD_B
#undef MFMA_Q
#undef BAR
#undef PRIO1
#undef PRIO0
#undef VMCNT
}

// ---------------------------------------------------------------------------
extern "C" void kernel_launch(void* const* d_in, const int* in_sizes, int n_in,
                              void* d_out, int out_size, void* d_ws, size_t ws_size,
                              hipStream_t stream) {
    const float* x      = (const float*)d_in[0];
    const float* prev_c = (const float*)d_in[1];
    const float* prev_h = (const float*)d_in[2];
    const float* kern   = (const float*)d_in[3];
    const float* rker   = (const float*)d_in[4];
    const float* bias   = (const float*)d_in[5];
    float* out = (float*)d_out;

    char* ws = (char*)d_ws;
    __bf16* Wcat = (__bf16*)ws;                              // 8 MB
    __bf16* A0   = (__bf16*)(ws + (size_t)8  * 1024 * 1024); // 32 MB
    __bf16* A1   = (__bf16*)(ws + (size_t)40 * 1024 * 1024); // 32 MB

    convert_A<<<12288, 256, 0, stream>>>(x, prev_c, A0, A1);
    repack_w<<<1024, 256, 0, stream>>>(kern, rker, Wcat);

    // grid: 512 blocks; bid%64 = m-panel (fast), bid/64 = n-panel (slow)
    lstm_gemm<<<512, 512, 0, stream>>>(A0, Wcat,
                                       prev_h,              bias,
                                       out,                 out + (size_t)BS,
                                       A1);
    lstm_gemm<<<512, 512, 0, stream>>>(A1, Wcat + (size_t)N_DIM * K_DIM,
                                       prev_h + (size_t)BS, bias + N_DIM,
                                       out + (size_t)2 * BS, out + (size_t)3 * BS,
                                       nullptr);
}